// Round 14
// baseline (210.223 us; speedup 1.0000x reference)
//
#include <hip/hip_runtime.h>
#include <hip/hip_bf16.h>
#include <cstdint>

// Problem dims
#define NBATCH 2
#define NS 2048
#define NDIM 1024
#define NHEAD 16
#define NDH 64
#define NBH 32  // NBATCH*NHEAD

typedef __bf16 bf16x8 __attribute__((ext_vector_type(8)));
typedef float f32x4 __attribute__((ext_vector_type(4)));

// exp(x/8) = 2^(x * log2(e)/8); Q is pre-scaled by this in the Q-GEMM epilogue
#define QK_EXP2_SCALE 0.1803368801111244f

#define WAITV(N) asm volatile("s_waitcnt vmcnt(" #N ")" ::: "memory")
#define FENCE asm volatile("" ::: "memory")

// Direct v_exp_f32 (2^x, ~1 ULP); OCML exp2f w/o -ffast-math is multi-op.
#define EXP2(x) __builtin_amdgcn_exp2f(x)

static __device__ __forceinline__ f32x4 mfma16(bf16x8 a, bf16x8 b, f32x4 c) {
  return __builtin_amdgcn_mfma_f32_16x16x32_bf16(a, b, c, 0, 0, 0);
}

static __device__ __forceinline__ void gload_lds16(const void* g, void* l) {
  __builtin_amdgcn_global_load_lds(
      (const __attribute__((address_space(1))) uint32_t*)g,
      (__attribute__((address_space(3))) uint32_t*)l, 16, 0, 0);
}

// ---------------------------------------------------------------------------
// Kernel 0a: fp32 -> bf16 convert for qs/ks/vs. out: [3][4096][1024] bf16
__global__ __launch_bounds__(256) void k_cvt_x(const float* __restrict__ q,
                                               const float* __restrict__ k,
                                               const float* __restrict__ v,
                                               __bf16* __restrict__ out) {
  const float* src = blockIdx.y == 0 ? q : (blockIdx.y == 1 ? k : v);
  __bf16* dst = out + (size_t)blockIdx.y * (size_t)(4096 * 1024);
  int i = blockIdx.x * 256 + threadIdx.x;  // chunk of 8 floats
  const float4* s4 = reinterpret_cast<const float4*>(src) + (size_t)i * 2;
  float4 a = s4[0], b = s4[1];
  bf16x8 o;
  o[0] = (__bf16)a.x; o[1] = (__bf16)a.y; o[2] = (__bf16)a.z; o[3] = (__bf16)a.w;
  o[4] = (__bf16)b.x; o[5] = (__bf16)b.y; o[6] = (__bf16)b.z; o[7] = (__bf16)b.w;
  *reinterpret_cast<bf16x8*>(dst + (size_t)i * 8) = o;
}

// ---------------------------------------------------------------------------
// Kernel 0b: convert+transpose W -> Wt[n][k] bf16 (y=0..3); y==4: mask->bias.
__global__ __launch_bounds__(256) void k_cvt_w(const float* __restrict__ Wq,
                                               const float* __restrict__ Wk,
                                               const float* __restrict__ Wv,
                                               const float* __restrict__ Wo,
                                               __bf16* __restrict__ out,
                                               const int* __restrict__ mask,
                                               float* __restrict__ biasf) {
  if (blockIdx.y == 4) {
    // softmax additive bias: 0 kept, -1e30 masked.  [2][2048] f32
    int t = blockIdx.x * 256 + threadIdx.x;
    if (t < NBATCH * NS) biasf[t] = mask[t] ? 0.f : -1e30f;
    return;
  }
  const float* W = blockIdx.y == 0 ? Wq : (blockIdx.y == 1 ? Wk
                   : (blockIdx.y == 2 ? Wv : Wo));
  __bf16* dst = out + (size_t)blockIdx.y * (size_t)(1024 * 1024);
  int t = blockIdx.x * 256 + threadIdx.x;  // 0..131071
  int n = t & 1023;
  int kc = t >> 10;  // 0..127
  bf16x8 o;
#pragma unroll
  for (int j = 0; j < 8; ++j) o[j] = (__bf16)W[(size_t)(kc * 8 + j) * 1024 + n];
  *reinterpret_cast<bf16x8*>(dst + (size_t)n * 1024 + kc * 8) = o;
}

// ---------------------------------------------------------------------------
// Kernel 0c (v2): transpose V per head via LDS tile (coalesced both sides).
// Old version stored 64 lanes x 16B at 4KB stride = 64 partial lines per
// instr (~8x write amplification). Now: 128s x 64d tile -> LDS [64][130]
// (pad 2 keeps 2B-write conflicts ~4-way) -> Vt rows written as 4x256B
// fully-covered line runs per instruction. Grid 512 = 2 blocks/CU.
__global__ __launch_bounds__(256) void k_tr_v(const __bf16* __restrict__ V,
                                              __bf16* __restrict__ Vt) {
  __shared__ __bf16 t[64][130];
  const int bh = blockIdx.x >> 4;          // 0..31
  const int s0 = (blockIdx.x & 15) * 128;  // s-tile of 128
  const int tid = threadIdx.x;
#pragma unroll
  for (int i = 0; i < 4; ++i) {
    int ch = tid + i * 256;        // 0..1023
    int s = ch >> 3, dc = ch & 7;  // s 0..127, d-chunk 0..7
    bf16x8 v = *reinterpret_cast<const bf16x8*>(
        V + ((size_t)bh * 2048 + s0 + s) * 64 + dc * 8);
#pragma unroll
    for (int j = 0; j < 8; ++j) t[dc * 8 + j][s] = v[j];
  }
  __syncthreads();
#pragma unroll
  for (int i = 0; i < 4; ++i) {
    int ch = tid + i * 256;         // 0..1023
    int d = ch >> 4, sc = ch & 15;  // d 0..63, s-chunk 0..15
    bf16x8 o;
#pragma unroll
    for (int j = 0; j < 8; ++j) o[j] = t[d][sc * 8 + j];
    *reinterpret_cast<bf16x8*>(Vt + ((size_t)bh * 64 + d) * 2048 + s0 +
                               sc * 8) = o;
  }
}

// ---------------------------------------------------------------------------
// GEMM: C[4096][1024] = A[4096][1024] * Bt^T + bias.  A row-major [m][k],
// Bt is [n][k] (k contiguous). 128x128 tile, BK=64, 4 waves, dbuf LDS.
// XCD-swizzled: blocks sharing an A-panel are co-resident on one XCD.
// mode 0: write bf16 to head layout [(b*16+h)][s][d], out + job*4194304;
//         job 0 (Q) additionally scaled by QK_EXP2_SCALE.
// mode 1: write fp32 row-major [m][n] (final output, non-temporal)
__global__ __launch_bounds__(256) void k_gemm(const __bf16* __restrict__ Abase,
                                              const __bf16* __restrict__ Btbase,
                                              const float* __restrict__ b0,
                                              const float* __restrict__ b1,
                                              const float* __restrict__ b2,
                                              void* __restrict__ outbase,
                                              int mode) {
  __shared__ __align__(16) char smem[65536];  // [2][A 16K | B 16K]
  const int job = blockIdx.y;
  const __bf16* A = Abase + (size_t)job * (size_t)(4096 * 1024);
  const __bf16* Bt = Btbase + (size_t)job * (size_t)(1024 * 1024);
  const float* bias = job == 0 ? b0 : (job == 1 ? b1 : b2);
  // XCD swizzle: xcd = x&7 gets mt = xcd*4 + (x>>6), all 8 nt co-resident
  const int x = blockIdx.x;
  const int mt = (x & 7) * 4 + (x >> 6);  // 0..31
  const int nt = (x >> 3) & 7;            // 0..7
  const int tid = threadIdx.x;
  const int w = tid >> 6, l = tid & 63;
  const int wr = w >> 1, wc = w & 1;

  auto stage = [&](int buf, int kt) {
    const int k0 = kt * 64;
    char* al = smem + buf * 32768;
    char* bl = al + 16384;
#pragma unroll
    for (int i = 0; i < 4; ++i) {
      int ch = tid + i * 256;  // 0..1023
      int r = ch >> 3, c = ch & 7;
      int cs = c ^ (r & 7);
      gload_lds16(A + (size_t)(mt * 128 + r) * 1024 + k0 + cs * 8, al + ch * 16);
      gload_lds16(Bt + (size_t)(nt * 128 + r) * 1024 + k0 + cs * 8, bl + ch * 16);
    }
  };

  f32x4 acc[4][4] = {};
  stage(0, 0);
  for (int kt = 0; kt < 16; ++kt) {
    __syncthreads();  // implicit vmcnt(0): stage(kt) complete for all waves
    if (kt + 1 < 16) stage((kt + 1) & 1, kt + 1);
    const char* al = smem + (kt & 1) * 32768;
    const char* bl = al + 16384;
#pragma unroll
    for (int ks = 0; ks < 2; ++ks) {
      bf16x8 af[4], bfr[4];
#pragma unroll
      for (int i = 0; i < 4; ++i) {
        int ra = wr * 64 + i * 16 + (l & 15);
        int ca = (ks * 4 + (l >> 4)) ^ (ra & 7);
        af[i] = *reinterpret_cast<const bf16x8*>(al + ra * 128 + ca * 16);
        int rb = wc * 64 + i * 16 + (l & 15);
        int cb = (ks * 4 + (l >> 4)) ^ (rb & 7);
        bfr[i] = *reinterpret_cast<const bf16x8*>(bl + rb * 128 + cb * 16);
      }
#pragma unroll
      for (int mi = 0; mi < 4; ++mi)
#pragma unroll
        for (int ni = 0; ni < 4; ++ni)
          acc[mi][ni] = mfma16(af[mi], bfr[ni], acc[mi][ni]);
    }
  }

  if (mode == 0) {
    const float sc = (job == 0) ? QK_EXP2_SCALE : 1.0f;
    __bf16* outp = (__bf16*)outbase + (size_t)job * (size_t)(NBH * NS * NDH);
#pragma unroll
    for (int mi = 0; mi < 4; ++mi)
#pragma unroll
      for (int ni = 0; ni < 4; ++ni)
#pragma unroll
        for (int r = 0; r < 4; ++r) {
          int m = mt * 128 + wr * 64 + mi * 16 + (l >> 4) * 4 + r;
          int n = nt * 128 + wc * 64 + ni * 16 + (l & 15);
          float v = (acc[mi][ni][r] + bias[n]) * sc;
          int b = m >> 11, s = m & 2047, h = n >> 6, d = n & 63;
          outp[(((size_t)(b * 16 + h)) * 2048 + s) * 64 + d] = (__bf16)v;
        }
  } else {
    float* outp = (float*)outbase;
#pragma unroll
    for (int mi = 0; mi < 4; ++mi)
#pragma unroll
      for (int ni = 0; ni < 4; ++ni)
#pragma unroll
        for (int r = 0; r < 4; ++r) {
          int m = mt * 128 + wr * 64 + mi * 16 + (l >> 4) * 4 + r;
          int n = nt * 128 + wc * 64 + ni * 16 + (l & 15);
          __builtin_nontemporal_store(acc[mi][ni][r] + bias[n],
                                      outp + (size_t)m * 1024 + n);
        }
  }
}

// ---------------------------------------------------------------------------
// Attention v9 (R11 winner, verbatim): two-pass in one kernel, NT attn
// stores, counted vmcnt (2-iteration store slack), 2 barriers/kt, coalesced
// stores through wave-private Pf32 LDS tile, hardware exp2.
// LDS: K dbuf @0/@16K (pass1 ring-3 @0/@16K/@32K), V dbuf @32K/@48K,
//      Pf32 per wave @64K + w*2K (8 KB), bias ring-3 @72K (3x512B).
__global__ __launch_bounds__(256, 2) void k_attn(
    const __bf16* __restrict__ Qw, const __bf16* __restrict__ Kw,
    const __bf16* __restrict__ Vt, const float* __restrict__ biasf,
    float* __restrict__ attn_out, __bf16* __restrict__ ctx_out) {
  __shared__ __align__(16) char smem[75264];
  // XCD swizzle: 512 blocks -> 64 contiguous work items (4 bh) per XCD
  const int wg = blockIdx.x;
  const int swz = (wg & 7) * 64 + (wg >> 3);
  const int qt = swz & 15;  // q-tile of 128
  const int bh = swz >> 4;  // 0..31
  const int b = bh >> 4;
  const int tid = threadIdx.x, w = tid >> 6, l = tid & 63;
  const int g = l >> 4, c = l & 15;
  const int qw = qt * 128 + w * 32;  // this wave's first q row
  const float* biasb = biasf + b * 2048;

  // Q fragments (B-operand): lane holds Q[qw+16mi+c][32ks+8g .. +8]
  bf16x8 qa[2][2];
#pragma unroll
  for (int mi = 0; mi < 2; ++mi)
#pragma unroll
    for (int ks = 0; ks < 2; ++ks)
      qa[mi][ks] = *reinterpret_cast<const bf16x8*>(
          Qw + ((size_t)bh * 2048 + qw + mi * 16 + c) * 64 + ks * 32 + g * 8);

  auto stageK = [&](char* dst, int kt) {
#pragma unroll
    for (int i = 0; i < 4; ++i) {
      int ch = tid + i * 256;  // 0..1023
      int r = ch >> 3, cc = ch & 7;
      int cs = cc ^ (r & 7);
      gload_lds16(Kw + ((size_t)bh * 2048 + kt * 128 + r) * 64 + cs * 8,
                  dst + ch * 16);
    }
  };
  auto stageV = [&](char* dst, int kt) {
#pragma unroll
    for (int i = 0; i < 4; ++i) {
      int ch = tid + i * 256;  // 0..1023
      int r = ch >> 4, cc = ch & 15;
      int cs = cc ^ (r & 15);
      gload_lds16(Vt + ((size_t)bh * 64 + r) * 2048 + kt * 128 + cs * 8,
                  dst + ch * 16);
    }
  };
  // 512 B of per-kt bias; all 4 waves write the same data (benign)
  auto stageBias = [&](int slot, int kt) {
    if (l < 32)
      gload_lds16(biasb + kt * 128 + l * 4, smem + 73728 + slot * 512);
  };

  // ---- Pass 1: masked rowsums of exp2(s+bias); K ring-3, 1 barrier/kt ----
  float rs[2] = {0.f, 0.f};
  stageK(smem, 0);
  stageBias(0, 0);
  int sl = 0;
  for (int kt = 0; kt < 16; ++kt) {
    int nx = (sl + 1 == 3) ? 0 : sl + 1;
    if (kt + 1 < 16) {
      stageK(smem + nx * 16384, kt + 1);
      stageBias(nx, kt + 1);
      WAITV(5);  // FIFO: [stage(kt):5][stage(kt+1):5] -> stage(kt) landed
    } else {
      WAITV(0);
    }
    __builtin_amdgcn_s_barrier();
    FENCE;
    const char* kl = smem + sl * 16384;
    const float* bl = (const float*)(smem + 73728 + sl * 512);
#pragma unroll
    for (int nb = 0; nb < 8; ++nb) {
      bf16x8 kb[2];
#pragma unroll
      for (int ks = 0; ks < 2; ++ks) {
        int r = nb * 16 + c;
        int cc = (ks * 4 + g) ^ (r & 7);
        kb[ks] = *reinterpret_cast<const bf16x8*>(kl + r * 128 + cc * 16);
      }
      f32x4 cinit = *reinterpret_cast<const f32x4*>(bl + nb * 16 + g * 4);
#pragma unroll
      for (int mi = 0; mi < 2; ++mi) {
        f32x4 s = mfma16(kb[0], qa[mi][0], cinit);
        s = mfma16(kb[1], qa[mi][1], s);
        rs[mi] += EXP2(s[0]) + EXP2(s[1]) + EXP2(s[2]) + EXP2(s[3]);
      }
    }
    sl = nx;
  }
  float inv_[2];
#pragma unroll
  for (int mi = 0; mi < 2; ++mi) {
    float v = rs[mi];
    v += __shfl_xor(v, 16, 64);
    v += __shfl_xor(v, 32, 64);
    inv_[mi] = v > 0.f ? 1.f / v : 0.f;
  }
  FENCE; __builtin_amdgcn_s_barrier(); FENCE;  // pass-1 readers done

  // ---- Pass 2: recompute, coalesced NT attn stores via Pf32 LDS, PV ----
  f32x4 ctx[2][4] = {};
  float* attnb = attn_out + (size_t)bh * 2048 * 2048;
  char* pF = smem + 65536 + w * 2048;  // wave-private P f32 [16 q][32 k]
  stageK(smem, 0);
  stageV(smem + 32768, 0);
  stageBias(0, 0);
  for (int kt = 0; kt < 16; ++kt) {
    if (kt + 1 < 16) {
      int nx3 = (kt + 1) % 3;
      stageK(smem + ((kt + 1) & 1) * 16384, kt + 1);
      stageV(smem + 32768 + ((kt + 1) & 1) * 16384, kt + 1);
      stageBias(nx3, kt + 1);
    }
    // FIFO: [stage(kt):9][stores(kt-1):16][stage(kt+1):9] -> 2-iter slack
    if (kt == 0) WAITV(9);
    else if (kt == 15) WAITV(16);
    else WAITV(25);
    FENCE; __builtin_amdgcn_s_barrier(); FENCE;
    const char* kl = smem + (kt & 1) * 16384;
    const char* vl = smem + 32768 + (kt & 1) * 16384;
    const float* bl = (const float*)(smem + 73728 + (kt % 3) * 512);
#pragma unroll
    for (int kc = 0; kc < 4; ++kc) {
      // hoist K fragments + bias for nb = 2kc, 2kc+1
      bf16x8 kbj[2][2];
      f32x4 cin[2];
#pragma unroll
      for (int j = 0; j < 2; ++j) {
        const int nb = kc * 2 + j;
#pragma unroll
        for (int ks = 0; ks < 2; ++ks) {
          int r = nb * 16 + c;
          int cc = (ks * 4 + g) ^ (r & 7);
          kbj[j][ks] = *reinterpret_cast<const bf16x8*>(kl + r * 128 + cc * 16);
        }
        cin[j] = *reinterpret_cast<const f32x4*>(bl + nb * 16 + g * 4);
      }
      // hoist V fragments for this 32-k chunk
      bf16x8 vb[4];
#pragma unroll
      for (int nd = 0; nd < 4; ++nd) {
        int dd = nd * 16 + c;
        int ch = (kc * 4 + g) ^ (dd & 15);
        vb[nd] = *reinterpret_cast<const bf16x8*>(vl + dd * 256 + ch * 16);
      }
#pragma unroll
      for (int mi = 0; mi < 2; ++mi) {
        // QK + exp -> Pf32 LDS (row c, chunk-XOR swizzle)
#pragma unroll
        for (int j = 0; j < 2; ++j) {
          f32x4 s = mfma16(kbj[j][0], qa[mi][0], cin[j]);
          s = mfma16(kbj[j][1], qa[mi][1], s);
          f32x4 p;
#pragma unroll
          for (int r = 0; r < 4; ++r) p[r] = EXP2(s[r]) * inv_[mi];
          *reinterpret_cast<f32x4*>(
              pF + c * 128 + (((j * 4 + g) ^ (c & 7)) * 16)) = p;
        }
        // PV A-fragment from Pf32 (k = kc*32 + g*8 .. +8), cvt to bf16
        bf16x8 pa;
        {
          f32x4 lo = *reinterpret_cast<const f32x4*>(
              pF + c * 128 + (((2 * g) ^ (c & 7)) * 16));
          f32x4 hi = *reinterpret_cast<const f32x4*>(
              pF + c * 128 + (((2 * g + 1) ^ (c & 7)) * 16));
          pa[0] = (__bf16)lo[0]; pa[1] = (__bf16)lo[1];
          pa[2] = (__bf16)lo[2]; pa[3] = (__bf16)lo[3];
          pa[4] = (__bf16)hi[0]; pa[5] = (__bf16)hi[1];
          pa[6] = (__bf16)hi[2]; pa[7] = (__bf16)hi[3];
        }
#pragma unroll
        for (int nd = 0; nd < 4; ++nd)
          ctx[mi][nd] = mfma16(pa, vb[nd], ctx[mi][nd]);
        // coalesced NT attn stores: 2 x 1 KB, each 8 rows x 128 B full lines
#pragma unroll
        for (int u = 0; u < 2; ++u) {
          int rr = u * 8 + (l >> 3);          // 0..15
          int ch = (l & 7) ^ (rr & 7);
          f32x4 pv = *reinterpret_cast<const f32x4*>(pF + rr * 128 + ch * 16);
          __builtin_nontemporal_store(
              pv, reinterpret_cast<f32x4*>(
                      attnb + (size_t)(qw + mi * 16 + rr) * 2048 + kt * 128 +
                      kc * 32 + (l & 7) * 4));
        }
      }
    }
    FENCE; __builtin_amdgcn_s_barrier(); FENCE;  // protect buf from stage(kt+2)
  }

  // ctx epilogue -> ws as [4096][1024] bf16 (row m = b*2048+s, col n = h*64+d)
  const int h = bh & 15;
#pragma unroll
  for (int mi = 0; mi < 2; ++mi)
#pragma unroll
    for (int nd = 0; nd < 4; ++nd)
#pragma unroll
      for (int r = 0; r < 4; ++r) {
        int m = b * 2048 + qw + mi * 16 + g * 4 + r;
        int n = h * 64 + nd * 16 + c;
        ctx_out[(size_t)m * 1024 + n] = (__bf16)ctx[mi][nd][r];
      }
}

// ---------------------------------------------------------------------------
extern "C" void kernel_launch(void* const* d_in, const int* in_sizes, int n_in,
                              void* d_out, int out_size, void* d_ws,
                              size_t ws_size, hipStream_t stream) {
  const float* qs = (const float*)d_in[0];
  const float* ks = (const float*)d_in[1];
  const float* vs = (const float*)d_in[2];
  const int* mask = (const int*)d_in[3];
  const float* Wq = (const float*)d_in[4];
  const float* bq = (const float*)d_in[5];
  const float* Wk = (const float*)d_in[6];
  const float* bk = (const float*)d_in[7];
  const float* Wv = (const float*)d_in[8];
  const float* bv = (const float*)d_in[9];
  const float* Wo = (const float*)d_in[10];
  const float* bo = (const float*)d_in[11];

  char* ws = (char*)d_ws;
  __bf16* Xb = (__bf16*)(ws);                    // [3][4096][1024] bf16
  __bf16* Wt = (__bf16*)(ws + 25165824);         // [4][1024][1024] bf16
  __bf16* QKV = (__bf16*)(ws + 58720256);        // [3][32][2048][64] bf16
  float* biasf = (float*)(ws + 83886080);        // [2][2048] f32
  __bf16* Vt = (__bf16*)(ws);                    // reuse X: [32][64][2048]
  __bf16* ctx = (__bf16*)(ws + 8388608);         // reuse X: [4096][1024]
  float* out = (float*)d_out;
  float* attn = out + (size_t)4194304;

  k_cvt_x<<<dim3(2048, 3), 256, 0, stream>>>(qs, ks, vs, Xb);
  k_cvt_w<<<dim3(512, 5), 256, 0, stream>>>(Wq, Wk, Wv, Wo, Wt, mask, biasf);
  k_gemm<<<dim3(256, 3), 256, 0, stream>>>(Xb, Wt, bq, bk, bv, QKV, 0);
  k_tr_v<<<dim3(512), 256, 0, stream>>>(QKV + (size_t)2 * 4194304, Vt);
  k_attn<<<dim3(512), 256, 0, stream>>>(QKV, QKV + (size_t)4194304, Vt, biasf,
                                        attn, ctx);
  k_gemm<<<dim3(256, 1), 256, 0, stream>>>(ctx, Wt + (size_t)3 * 1048576, bo,
                                           bo, bo, d_out, 1);
}

// Round 15
// 209.615 us; speedup vs baseline: 1.0029x; 1.0029x over previous
//
#include <hip/hip_runtime.h>
#include <hip/hip_bf16.h>
#include <cstdint>

// Problem dims
#define NBATCH 2
#define NS 2048
#define NDIM 1024
#define NHEAD 16
#define NDH 64
#define NBH 32  // NBATCH*NHEAD

typedef __bf16 bf16x8 __attribute__((ext_vector_type(8)));
typedef float f32x4 __attribute__((ext_vector_type(4)));

// exp(x/8) = 2^(x * log2(e)/8); Q is pre-scaled by this in the Q-GEMM epilogue
#define QK_EXP2_SCALE 0.1803368801111244f

#define WAITV(N) asm volatile("s_waitcnt vmcnt(" #N ")" ::: "memory")
#define FENCE asm volatile("" ::: "memory")

// Direct v_exp_f32 (2^x, ~1 ULP); OCML exp2f w/o -ffast-math is multi-op.
#define EXP2(x) __builtin_amdgcn_exp2f(x)

static __device__ __forceinline__ f32x4 mfma16(bf16x8 a, bf16x8 b, f32x4 c) {
  return __builtin_amdgcn_mfma_f32_16x16x32_bf16(a, b, c, 0, 0, 0);
}

static __device__ __forceinline__ void gload_lds16(const void* g, void* l) {
  __builtin_amdgcn_global_load_lds(
      (const __attribute__((address_space(1))) uint32_t*)g,
      (__attribute__((address_space(3))) uint32_t*)l, 16, 0, 0);
}

// ---------------------------------------------------------------------------
// Kernel 0a: fp32 -> bf16 convert for qs/ks/vs. out: [3][4096][1024] bf16
__global__ __launch_bounds__(256) void k_cvt_x(const float* __restrict__ q,
                                               const float* __restrict__ k,
                                               const float* __restrict__ v,
                                               __bf16* __restrict__ out) {
  const float* src = blockIdx.y == 0 ? q : (blockIdx.y == 1 ? k : v);
  __bf16* dst = out + (size_t)blockIdx.y * (size_t)(4096 * 1024);
  int i = blockIdx.x * 256 + threadIdx.x;  // chunk of 8 floats
  const float4* s4 = reinterpret_cast<const float4*>(src) + (size_t)i * 2;
  float4 a = s4[0], b = s4[1];
  bf16x8 o;
  o[0] = (__bf16)a.x; o[1] = (__bf16)a.y; o[2] = (__bf16)a.z; o[3] = (__bf16)a.w;
  o[4] = (__bf16)b.x; o[5] = (__bf16)b.y; o[6] = (__bf16)b.z; o[7] = (__bf16)b.w;
  *reinterpret_cast<bf16x8*>(dst + (size_t)i * 8) = o;
}

// ---------------------------------------------------------------------------
// Kernel 0b: convert+transpose W -> Wt[n][k] bf16 (y=0..3); y==4: mask->bias.
__global__ __launch_bounds__(256) void k_cvt_w(const float* __restrict__ Wq,
                                               const float* __restrict__ Wk,
                                               const float* __restrict__ Wv,
                                               const float* __restrict__ Wo,
                                               __bf16* __restrict__ out,
                                               const int* __restrict__ mask,
                                               float* __restrict__ biasf) {
  if (blockIdx.y == 4) {
    // softmax additive bias: 0 kept, -1e30 masked.  [2][2048] f32
    int t = blockIdx.x * 256 + threadIdx.x;
    if (t < NBATCH * NS) biasf[t] = mask[t] ? 0.f : -1e30f;
    return;
  }
  const float* W = blockIdx.y == 0 ? Wq : (blockIdx.y == 1 ? Wk
                   : (blockIdx.y == 2 ? Wv : Wo));
  __bf16* dst = out + (size_t)blockIdx.y * (size_t)(1024 * 1024);
  int t = blockIdx.x * 256 + threadIdx.x;  // 0..131071
  int n = t & 1023;
  int kc = t >> 10;  // 0..127
  bf16x8 o;
#pragma unroll
  for (int j = 0; j < 8; ++j) o[j] = (__bf16)W[(size_t)(kc * 8 + j) * 1024 + n];
  *reinterpret_cast<bf16x8*>(dst + (size_t)n * 1024 + kc * 8) = o;
}

// ---------------------------------------------------------------------------
// Kernel 0c (v2): transpose V per head via LDS tile (coalesced both sides).
// Old version stored 64 lanes x 16B at 4KB stride = 64 partial lines per
// instr (~8x write amplification). Now: 128s x 64d tile -> LDS [64][130]
// (pad 2 keeps 2B-write conflicts ~4-way) -> Vt rows written as 4x256B
// fully-covered line runs per instruction. Grid 512 = 2 blocks/CU.
__global__ __launch_bounds__(256) void k_tr_v(const __bf16* __restrict__ V,
                                              __bf16* __restrict__ Vt) {
  __shared__ __bf16 t[64][130];
  const int bh = blockIdx.x >> 4;          // 0..31
  const int s0 = (blockIdx.x & 15) * 128;  // s-tile of 128
  const int tid = threadIdx.x;
#pragma unroll
  for (int i = 0; i < 4; ++i) {
    int ch = tid + i * 256;        // 0..1023
    int s = ch >> 3, dc = ch & 7;  // s 0..127, d-chunk 0..7
    bf16x8 v = *reinterpret_cast<const bf16x8*>(
        V + ((size_t)bh * 2048 + s0 + s) * 64 + dc * 8);
#pragma unroll
    for (int j = 0; j < 8; ++j) t[dc * 8 + j][s] = v[j];
  }
  __syncthreads();
#pragma unroll
  for (int i = 0; i < 4; ++i) {
    int ch = tid + i * 256;         // 0..1023
    int d = ch >> 4, sc = ch & 15;  // d 0..63, s-chunk 0..15
    bf16x8 o;
#pragma unroll
    for (int j = 0; j < 8; ++j) o[j] = t[d][sc * 8 + j];
    *reinterpret_cast<bf16x8*>(Vt + ((size_t)bh * 64 + d) * 2048 + s0 +
                               sc * 8) = o;
  }
}

// ---------------------------------------------------------------------------
// GEMM: C[4096][1024] = A[4096][1024] * Bt^T + bias.  A row-major [m][k],
// Bt is [n][k] (k contiguous). 128x128 tile, BK=64, 4 waves, dbuf LDS.
// XCD-swizzled: blocks sharing an A-panel are co-resident on one XCD.
// mode 0: write bf16 to head layout [(b*16+h)][s][d], out + job*4194304;
//         job 0 (Q) additionally scaled by QK_EXP2_SCALE.
// mode 1: write fp32 row-major [m][n] (final output, non-temporal)
__global__ __launch_bounds__(256) void k_gemm(const __bf16* __restrict__ Abase,
                                              const __bf16* __restrict__ Btbase,
                                              const float* __restrict__ b0,
                                              const float* __restrict__ b1,
                                              const float* __restrict__ b2,
                                              void* __restrict__ outbase,
                                              int mode) {
  __shared__ __align__(16) char smem[65536];  // [2][A 16K | B 16K]
  const int job = blockIdx.y;
  const __bf16* A = Abase + (size_t)job * (size_t)(4096 * 1024);
  const __bf16* Bt = Btbase + (size_t)job * (size_t)(1024 * 1024);
  const float* bias = job == 0 ? b0 : (job == 1 ? b1 : b2);
  // XCD swizzle: xcd = x&7 gets mt = xcd*4 + (x>>6), all 8 nt co-resident
  const int x = blockIdx.x;
  const int mt = (x & 7) * 4 + (x >> 6);  // 0..31
  const int nt = (x >> 3) & 7;            // 0..7
  const int tid = threadIdx.x;
  const int w = tid >> 6, l = tid & 63;
  const int wr = w >> 1, wc = w & 1;

  auto stage = [&](int buf, int kt) {
    const int k0 = kt * 64;
    char* al = smem + buf * 32768;
    char* bl = al + 16384;
#pragma unroll
    for (int i = 0; i < 4; ++i) {
      int ch = tid + i * 256;  // 0..1023
      int r = ch >> 3, c = ch & 7;
      int cs = c ^ (r & 7);
      gload_lds16(A + (size_t)(mt * 128 + r) * 1024 + k0 + cs * 8, al + ch * 16);
      gload_lds16(Bt + (size_t)(nt * 128 + r) * 1024 + k0 + cs * 8, bl + ch * 16);
    }
  };

  f32x4 acc[4][4] = {};
  stage(0, 0);
  for (int kt = 0; kt < 16; ++kt) {
    __syncthreads();  // implicit vmcnt(0): stage(kt) complete for all waves
    if (kt + 1 < 16) stage((kt + 1) & 1, kt + 1);
    const char* al = smem + (kt & 1) * 32768;
    const char* bl = al + 16384;
#pragma unroll
    for (int ks = 0; ks < 2; ++ks) {
      bf16x8 af[4], bfr[4];
#pragma unroll
      for (int i = 0; i < 4; ++i) {
        int ra = wr * 64 + i * 16 + (l & 15);
        int ca = (ks * 4 + (l >> 4)) ^ (ra & 7);
        af[i] = *reinterpret_cast<const bf16x8*>(al + ra * 128 + ca * 16);
        int rb = wc * 64 + i * 16 + (l & 15);
        int cb = (ks * 4 + (l >> 4)) ^ (rb & 7);
        bfr[i] = *reinterpret_cast<const bf16x8*>(bl + rb * 128 + cb * 16);
      }
#pragma unroll
      for (int mi = 0; mi < 4; ++mi)
#pragma unroll
        for (int ni = 0; ni < 4; ++ni)
          acc[mi][ni] = mfma16(af[mi], bfr[ni], acc[mi][ni]);
    }
  }

  if (mode == 0) {
    const float sc = (job == 0) ? QK_EXP2_SCALE : 1.0f;
    __bf16* outp = (__bf16*)outbase + (size_t)job * (size_t)(NBH * NS * NDH);
#pragma unroll
    for (int mi = 0; mi < 4; ++mi)
#pragma unroll
      for (int ni = 0; ni < 4; ++ni)
#pragma unroll
        for (int r = 0; r < 4; ++r) {
          int m = mt * 128 + wr * 64 + mi * 16 + (l >> 4) * 4 + r;
          int n = nt * 128 + wc * 64 + ni * 16 + (l & 15);
          float v = (acc[mi][ni][r] + bias[n]) * sc;
          int b = m >> 11, s = m & 2047, h = n >> 6, d = n & 63;
          outp[(((size_t)(b * 16 + h)) * 2048 + s) * 64 + d] = (__bf16)v;
        }
  } else {
    float* outp = (float*)outbase;
#pragma unroll
    for (int mi = 0; mi < 4; ++mi)
#pragma unroll
      for (int ni = 0; ni < 4; ++ni)
#pragma unroll
        for (int r = 0; r < 4; ++r) {
          int m = mt * 128 + wr * 64 + mi * 16 + (l >> 4) * 4 + r;
          int n = nt * 128 + wc * 64 + ni * 16 + (l & 15);
          __builtin_nontemporal_store(acc[mi][ni][r] + bias[n],
                                      outp + (size_t)m * 1024 + n);
        }
  }
}

// ---------------------------------------------------------------------------
// Attention v9 (R11 winner, verbatim): two-pass in one kernel, NT attn
// stores, counted vmcnt (2-iteration store slack), 2 barriers/kt, coalesced
// stores through wave-private Pf32 LDS tile, hardware exp2.
// LDS: K dbuf @0/@16K (pass1 ring-3 @0/@16K/@32K), V dbuf @32K/@48K,
//      Pf32 per wave @64K + w*2K (8 KB), bias ring-3 @72K (3x512B).
__global__ __launch_bounds__(256, 2) void k_attn(
    const __bf16* __restrict__ Qw, const __bf16* __restrict__ Kw,
    const __bf16* __restrict__ Vt, const float* __restrict__ biasf,
    float* __restrict__ attn_out, __bf16* __restrict__ ctx_out) {
  __shared__ __align__(16) char smem[75264];
  // XCD swizzle: 512 blocks -> 64 contiguous work items (4 bh) per XCD
  const int wg = blockIdx.x;
  const int swz = (wg & 7) * 64 + (wg >> 3);
  const int qt = swz & 15;  // q-tile of 128
  const int bh = swz >> 4;  // 0..31
  const int b = bh >> 4;
  const int tid = threadIdx.x, w = tid >> 6, l = tid & 63;
  const int g = l >> 4, c = l & 15;
  const int qw = qt * 128 + w * 32;  // this wave's first q row
  const float* biasb = biasf + b * 2048;

  // Q fragments (B-operand): lane holds Q[qw+16mi+c][32ks+8g .. +8]
  bf16x8 qa[2][2];
#pragma unroll
  for (int mi = 0; mi < 2; ++mi)
#pragma unroll
    for (int ks = 0; ks < 2; ++ks)
      qa[mi][ks] = *reinterpret_cast<const bf16x8*>(
          Qw + ((size_t)bh * 2048 + qw + mi * 16 + c) * 64 + ks * 32 + g * 8);

  auto stageK = [&](char* dst, int kt) {
#pragma unroll
    for (int i = 0; i < 4; ++i) {
      int ch = tid + i * 256;  // 0..1023
      int r = ch >> 3, cc = ch & 7;
      int cs = cc ^ (r & 7);
      gload_lds16(Kw + ((size_t)bh * 2048 + kt * 128 + r) * 64 + cs * 8,
                  dst + ch * 16);
    }
  };
  auto stageV = [&](char* dst, int kt) {
#pragma unroll
    for (int i = 0; i < 4; ++i) {
      int ch = tid + i * 256;  // 0..1023
      int r = ch >> 4, cc = ch & 15;
      int cs = cc ^ (r & 15);
      gload_lds16(Vt + ((size_t)bh * 64 + r) * 2048 + kt * 128 + cs * 8,
                  dst + ch * 16);
    }
  };
  // 512 B of per-kt bias; all 4 waves write the same data (benign)
  auto stageBias = [&](int slot, int kt) {
    if (l < 32)
      gload_lds16(biasb + kt * 128 + l * 4, smem + 73728 + slot * 512);
  };

  // ---- Pass 1: masked rowsums of exp2(s+bias); K ring-3, 1 barrier/kt ----
  float rs[2] = {0.f, 0.f};
  stageK(smem, 0);
  stageBias(0, 0);
  int sl = 0;
  for (int kt = 0; kt < 16; ++kt) {
    int nx = (sl + 1 == 3) ? 0 : sl + 1;
    if (kt + 1 < 16) {
      stageK(smem + nx * 16384, kt + 1);
      stageBias(nx, kt + 1);
      WAITV(5);  // FIFO: [stage(kt):5][stage(kt+1):5] -> stage(kt) landed
    } else {
      WAITV(0);
    }
    __builtin_amdgcn_s_barrier();
    FENCE;
    const char* kl = smem + sl * 16384;
    const float* bl = (const float*)(smem + 73728 + sl * 512);
#pragma unroll
    for (int nb = 0; nb < 8; ++nb) {
      bf16x8 kb[2];
#pragma unroll
      for (int ks = 0; ks < 2; ++ks) {
        int r = nb * 16 + c;
        int cc = (ks * 4 + g) ^ (r & 7);
        kb[ks] = *reinterpret_cast<const bf16x8*>(kl + r * 128 + cc * 16);
      }
      f32x4 cinit = *reinterpret_cast<const f32x4*>(bl + nb * 16 + g * 4);
#pragma unroll
      for (int mi = 0; mi < 2; ++mi) {
        f32x4 s = mfma16(kb[0], qa[mi][0], cinit);
        s = mfma16(kb[1], qa[mi][1], s);
        rs[mi] += EXP2(s[0]) + EXP2(s[1]) + EXP2(s[2]) + EXP2(s[3]);
      }
    }
    sl = nx;
  }
  float inv_[2];
#pragma unroll
  for (int mi = 0; mi < 2; ++mi) {
    float v = rs[mi];
    v += __shfl_xor(v, 16, 64);
    v += __shfl_xor(v, 32, 64);
    inv_[mi] = v > 0.f ? 1.f / v : 0.f;
  }
  FENCE; __builtin_amdgcn_s_barrier(); FENCE;  // pass-1 readers done

  // ---- Pass 2: recompute, coalesced NT attn stores via Pf32 LDS, PV ----
  f32x4 ctx[2][4] = {};
  float* attnb = attn_out + (size_t)bh * 2048 * 2048;
  char* pF = smem + 65536 + w * 2048;  // wave-private P f32 [16 q][32 k]
  stageK(smem, 0);
  stageV(smem + 32768, 0);
  stageBias(0, 0);
  for (int kt = 0; kt < 16; ++kt) {
    if (kt + 1 < 16) {
      int nx3 = (kt + 1) % 3;
      stageK(smem + ((kt + 1) & 1) * 16384, kt + 1);
      stageV(smem + 32768 + ((kt + 1) & 1) * 16384, kt + 1);
      stageBias(nx3, kt + 1);
    }
    // FIFO: [stage(kt):9][stores(kt-1):16][stage(kt+1):9] -> 2-iter slack
    if (kt == 0) WAITV(9);
    else if (kt == 15) WAITV(16);
    else WAITV(25);
    FENCE; __builtin_amdgcn_s_barrier(); FENCE;
    const char* kl = smem + (kt & 1) * 16384;
    const char* vl = smem + 32768 + (kt & 1) * 16384;
    const float* bl = (const float*)(smem + 73728 + (kt % 3) * 512);
#pragma unroll
    for (int kc = 0; kc < 4; ++kc) {
      // hoist K fragments + bias for nb = 2kc, 2kc+1
      bf16x8 kbj[2][2];
      f32x4 cin[2];
#pragma unroll
      for (int j = 0; j < 2; ++j) {
        const int nb = kc * 2 + j;
#pragma unroll
        for (int ks = 0; ks < 2; ++ks) {
          int r = nb * 16 + c;
          int cc = (ks * 4 + g) ^ (r & 7);
          kbj[j][ks] = *reinterpret_cast<const bf16x8*>(kl + r * 128 + cc * 16);
        }
        cin[j] = *reinterpret_cast<const f32x4*>(bl + nb * 16 + g * 4);
      }
      // hoist V fragments for this 32-k chunk
      bf16x8 vb[4];
#pragma unroll
      for (int nd = 0; nd < 4; ++nd) {
        int dd = nd * 16 + c;
        int ch = (kc * 4 + g) ^ (dd & 15);
        vb[nd] = *reinterpret_cast<const bf16x8*>(vl + dd * 256 + ch * 16);
      }
#pragma unroll
      for (int mi = 0; mi < 2; ++mi) {
        // QK + exp -> Pf32 LDS (row c, chunk-XOR swizzle)
#pragma unroll
        for (int j = 0; j < 2; ++j) {
          f32x4 s = mfma16(kbj[j][0], qa[mi][0], cin[j]);
          s = mfma16(kbj[j][1], qa[mi][1], s);
          f32x4 p;
#pragma unroll
          for (int r = 0; r < 4; ++r) p[r] = EXP2(s[r]) * inv_[mi];
          *reinterpret_cast<f32x4*>(
              pF + c * 128 + (((j * 4 + g) ^ (c & 7)) * 16)) = p;
        }
        // PV A-fragment from Pf32 (k = kc*32 + g*8 .. +8), cvt to bf16
        bf16x8 pa;
        {
          f32x4 lo = *reinterpret_cast<const f32x4*>(
              pF + c * 128 + (((2 * g) ^ (c & 7)) * 16));
          f32x4 hi = *reinterpret_cast<const f32x4*>(
              pF + c * 128 + (((2 * g + 1) ^ (c & 7)) * 16));
          pa[0] = (__bf16)lo[0]; pa[1] = (__bf16)lo[1];
          pa[2] = (__bf16)lo[2]; pa[3] = (__bf16)lo[3];
          pa[4] = (__bf16)hi[0]; pa[5] = (__bf16)hi[1];
          pa[6] = (__bf16)hi[2]; pa[7] = (__bf16)hi[3];
        }
#pragma unroll
        for (int nd = 0; nd < 4; ++nd)
          ctx[mi][nd] = mfma16(pa, vb[nd], ctx[mi][nd]);
        // coalesced NT attn stores: 2 x 1 KB, each 8 rows x 128 B full lines
#pragma unroll
        for (int u = 0; u < 2; ++u) {
          int rr = u * 8 + (l >> 3);          // 0..15
          int ch = (l & 7) ^ (rr & 7);
          f32x4 pv = *reinterpret_cast<const f32x4*>(pF + rr * 128 + ch * 16);
          __builtin_nontemporal_store(
              pv, reinterpret_cast<f32x4*>(
                      attnb + (size_t)(qw + mi * 16 + rr) * 2048 + kt * 128 +
                      kc * 32 + (l & 7) * 4));
        }
      }
    }
    FENCE; __builtin_amdgcn_s_barrier(); FENCE;  // protect buf from stage(kt+2)
  }

  // ctx epilogue -> ws as [4096][1024] bf16 (row m = b*2048+s, col n = h*64+d)
  const int h = bh & 15;
#pragma unroll
  for (int mi = 0; mi < 2; ++mi)
#pragma unroll
    for (int nd = 0; nd < 4; ++nd)
#pragma unroll
      for (int r = 0; r < 4; ++r) {
        int m = b * 2048 + qw + mi * 16 + g * 4 + r;
        int n = h * 64 + nd * 16 + c;
        ctx_out[(size_t)m * 1024 + n] = (__bf16)ctx[mi][nd][r];
      }
}

// ---------------------------------------------------------------------------
extern "C" void kernel_launch(void* const* d_in, const int* in_sizes, int n_in,
                              void* d_out, int out_size, void* d_ws,
                              size_t ws_size, hipStream_t stream) {
  const float* qs = (const float*)d_in[0];
  const float* ks = (const float*)d_in[1];
  const float* vs = (const float*)d_in[2];
  const int* mask = (const int*)d_in[3];
  const float* Wq = (const float*)d_in[4];
  const float* bq = (const float*)d_in[5];
  const float* Wk = (const float*)d_in[6];
  const float* bk = (const float*)d_in[7];
  const float* Wv = (const float*)d_in[8];
  const float* bv = (const float*)d_in[9];
  const float* Wo = (const float*)d_in[10];
  const float* bo = (const float*)d_in[11];

  char* ws = (char*)d_ws;
  __bf16* Xb = (__bf16*)(ws);                    // [3][4096][1024] bf16
  __bf16* Wt = (__bf16*)(ws + 25165824);         // [4][1024][1024] bf16
  __bf16* QKV = (__bf16*)(ws + 58720256);        // [3][32][2048][64] bf16
  float* biasf = (float*)(ws + 83886080);        // [2][2048] f32
  __bf16* Vt = (__bf16*)(ws);                    // reuse X: [32][64][2048]
  __bf16* ctx = (__bf16*)(ws + 8388608);         // reuse X: [4096][1024]
  float* out = (float*)d_out;
  float* attn = out + (size_t)4194304;

  k_cvt_x<<<dim3(2048, 3), 256, 0, stream>>>(qs, ks, vs, Xb);
  k_cvt_w<<<dim3(512, 5), 256, 0, stream>>>(Wq, Wk, Wv, Wo, Wt, mask, biasf);
  k_gemm<<<dim3(256, 3), 256, 0, stream>>>(Xb, Wt, bq, bk, bv, QKV, 0);
  k_tr_v<<<dim3(512), 256, 0, stream>>>(QKV + (size_t)2 * 4194304, Vt);
  k_attn<<<dim3(512), 256, 0, stream>>>(QKV, QKV + (size_t)4194304, Vt, biasf,
                                        attn, ctx);
  k_gemm<<<dim3(256, 1), 256, 0, stream>>>(ctx, Wt + (size_t)3 * 1048576, bo,
                                           bo, bo, d_out, 1);
}